// Round 7
// baseline (1493.866 us; speedup 1.0000x reference)
//
#include <hip/hip_runtime.h>

#define HN 192
#define TT 2048
#define NCLS 12
#define ROWB 768
#define SEGB 288
// LDS layout (bytes)
#define L0_PAD    147456           // zero row (768B) right after W0
#define LDS_LIST0 148224           // 2 bufs x 3 segs x 288B = 1728
#define LDS_CNT   149952           // 2 x 16B (int4 of per-wave counts)
#define LDS_S0    149984           // 2 x 768B s0 double buffer
#define LDS_LIST1 151520           // wave3-private list, 200*4B
#define LDS_FEAT  152320           // 768B
#define LDS_TOTAL 153088

// ws layout (floats): [w0 rows 0..191][zero row][w1 rows 0..191][256f pad]
__global__ void snn_pack_k(const float* __restrict__ Wc, float* __restrict__ ws) {
  int idx = blockIdx.x * 256 + threadIdx.x;
  if (idx < HN * HN) {                       // layer 0: Wc[0][i][j] -> ws[j*192+i]
    int i = idx / HN, j = idx % HN;
    ws[j * HN + i] = Wc[idx];
  } else if (idx < 2 * HN * HN) {            // layer 1 -> rows 193..384
    int r = idx - HN * HN;
    int i = r / HN, j = r % HN;
    ws[(193 + j) * HN + i] = Wc[idx];
  } else {
    int r = idx - 2 * HN * HN;
    if (r < HN) ws[192 * HN + r] = 0.0f;     // zero row
    if (r < 256) ws[385 * HN + r] = 0.0f;    // tail pad
  }
}

struct F3 { float x, y, z; };

__device__ __forceinline__ int lanecnt_lt(unsigned long long m) {
  return __builtin_amdgcn_mbcnt_hi((unsigned)(m >> 32),
           __builtin_amdgcn_mbcnt_lo((unsigned)m, 0u));
}

#define READC(da, db, base, c) do { \
  da = *(const int4*)((base) + (c) * 32); \
  db = *(const int4*)((base) + (c) * 32 + 16); } while (0)

#define ISS8L0(p, ca, cb) do { \
  p##0 = *(const float*)(ldsb + (unsigned)(ca).x + nn4); \
  p##1 = *(const float*)(ldsb + (unsigned)(ca).y + nn4); \
  p##2 = *(const float*)(ldsb + (unsigned)(ca).z + nn4); \
  p##3 = *(const float*)(ldsb + (unsigned)(ca).w + nn4); \
  p##4 = *(const float*)(ldsb + (unsigned)(cb).x + nn4); \
  p##5 = *(const float*)(ldsb + (unsigned)(cb).y + nn4); \
  p##6 = *(const float*)(ldsb + (unsigned)(cb).z + nn4); \
  p##7 = *(const float*)(ldsb + (unsigned)(cb).w + nn4); } while (0)

#define CONS8F(acc, p) acc += ((((p##0) + (p##1)) + ((p##2) + (p##3))) + \
                               (((p##4) + (p##5)) + ((p##6) + (p##7))))

#define ISS8W1(p, ca, cb) do { \
  p##0 = *(const F3*)(w1zb + (unsigned)(ca).x + ln12); \
  p##1 = *(const F3*)(w1zb + (unsigned)(ca).y + ln12); \
  p##2 = *(const F3*)(w1zb + (unsigned)(ca).z + ln12); \
  p##3 = *(const F3*)(w1zb + (unsigned)(ca).w + ln12); \
  p##4 = *(const F3*)(w1zb + (unsigned)(cb).x + ln12); \
  p##5 = *(const F3*)(w1zb + (unsigned)(cb).y + ln12); \
  p##6 = *(const F3*)(w1zb + (unsigned)(cb).z + ln12); \
  p##7 = *(const F3*)(w1zb + (unsigned)(cb).w + ln12); } while (0)

#define CONS8V3(p) do { \
  a1x += ((((p##0).x + (p##1).x) + ((p##2).x + (p##3).x)) + \
          (((p##4).x + (p##5).x) + ((p##6).x + (p##7).x))); \
  a1y += ((((p##0).y + (p##1).y) + ((p##2).y + (p##3).y)) + \
          (((p##4).y + (p##5).y) + ((p##6).y + (p##7).y))); \
  a1z += ((((p##0).z + (p##1).z) + ((p##2).z + (p##3).z)) + \
          (((p##4).z + (p##5).z) + ((p##6).z + (p##7).z))); \
} while (0)

// 4 waves per batch. Waves 0-2: L0 slice, 1 neuron/lane. The 3 per-producer
// list segments are gathered as ONE virtually-concatenated pipeline: heads
// (group 0 of each segment, index chunks prefetched pre-barrier) issued
// unconditionally, remaining groups base-selected via SGPR cselect with all
// index READCs issued before any consume. Wave 3: all of L1, global gather
// in flight across the whole step. One __syncthreads per timestep.
__global__ __launch_bounds__(256, 1) void snn_main_k(
    const float* __restrict__ x, const float* __restrict__ W_in,
    const float* __restrict__ b_in, const float* __restrict__ b_cells,
    const float* __restrict__ W_head, const float* __restrict__ b_head,
    const float* __restrict__ ws, float* __restrict__ out)
{
  extern __shared__ char lds[];
  const int tid = threadIdx.x;
  const int ln  = tid & 63;
  const int wv  = tid >> 6;          // 0..3
  const bool isW0 = (wv < 3);
  const int b   = blockIdx.x;
  const char* ldsb = lds;
  char* list1b = lds + LDS_LIST1;
  float* feat  = (float*)(lds + LDS_FEAT);
  const char* w1zb = (const char*)ws + 192 * ROWB;   // zero row = L1 offset base
  const unsigned nn4  = (unsigned)tid << 2;          // L0: neuron = tid (wv<3)
  const unsigned ln12 = (unsigned)ln * 12;

  // stage W0 (9216 float4), zero the state area, pre-fill list0 with pads
  {
    const float4* src = (const float4*)ws;
    float4* dst = (float4*)lds;
    for (int i = tid; i < (192 * ROWB) / 16; i += 256) dst[i] = src[i];
    float4 z4 = make_float4(0.f, 0.f, 0.f, 0.f);
    float4* zr = (float4*)(lds + L0_PAD);
    for (int i = tid; i < (LDS_TOTAL - L0_PAD) / 16; i += 256) zr[i] = z4;
  }
  __syncthreads();
  {  // t=0 reads parity-1 list0 unconditionally: must hold pad offsets
    for (int i = tid; i < (6 * SEGB) / 4; i += 256)
      *(int*)(lds + LDS_LIST0 + 4 * i) = L0_PAD;
  }
  __syncthreads();

  // ---- L0 per-lane constants (neuron nn = tid, valid for wv<3) ----
  const int nnc = isW0 ? tid : 0;
  const float wi0 = W_in[nnc * 3 + 0];
  const float wi1 = W_in[nnc * 3 + 1];
  const float wi2 = W_in[nnc * 3 + 2];
  const float zb  = b_in[nnc] + b_cells[nnc];
  // ---- wave3 per-lane constants (neurons 3ln..3ln+2) ----
  const float b1z0 = b_cells[HN + 3 * ln + 0];
  const float b1z1 = b_cells[HN + 3 * ln + 1];
  const float b1z2 = b_cells[HN + 3 * ln + 2];
  const int vo10 = (3 * ln + 1) * ROWB;
  const int vo11 = (3 * ln + 2) * ROWB;
  const int vo12 = (3 * ln + 3) * ROWB;

  const float* __restrict__ xb = x + (size_t)b * TT * 3;

  // persistent state
  float v0 = 0.0f;                                   // L0 (waves 0-2)
  float v10 = 0.f, v11 = 0.f, v12 = 0.f;             // L1 (wave 3)
  float cnt0 = 0.f, cnt1 = 0.f, cnt2 = 0.f;
  int ngl = 0;
  F3 gA0,gA1,gA2,gA3,gA4,gA5,gA6,gA7;
  F3 gB0,gB1,gB2,gB3,gB4,gB5,gB6,gB7;
  F3 gC0,gC1,gC2,gC3,gC4,gC5,gC6,gC7;
  F3 gD0,gD1,gD2,gD3,gD4,gD5,gD6,gD7;
  // L0 prefetch state
  int4 cntv = {0, 0, 0, 0};
  int4 p0a = {0,0,0,0}, p0b = {0,0,0,0}, p1a = {0,0,0,0},
       p1b = {0,0,0,0}, p2a = {0,0,0,0}, p2b = {0,0,0,0};
  const char* l0r = lds + LDS_LIST0 + 864;           // parity-1 (pad-filled) for t=0
  float x0 = xb[0], x1 = xb[1], x2 = xb[2];

  #pragma unroll 1
  for (int t = 0; t < TT; ++t) {
    const int wp = t & 1;                            // write parity this step

    if (isW0) {
      // ================= waves 0-2: layer-0 slice =================
      const float z = x0 * wi0 + x1 * wi1 + x2 * wi2 + zb;
      float a0 = 0.f;
      float hA0,hA1,hA2,hA3,hA4,hA5,hA6,hA7;
      float hB0,hB1,hB2,hB3,hB4,hB5,hB6,hB7;
      float hC0,hC1,hC2,hC3,hC4,hC5,hC6,hC7;
      float hD0,hD1,hD2,hD3,hD4,hD5,hD6,hD7;

      // heads: group 0 of each segment (pads make empty segments safe)
      ISS8L0(hA, p0a, p0b);
      ISS8L0(hB, p1a, p1b);
      ISS8L0(hC, p2a, p2b);

      const int ns0 = __builtin_amdgcn_readfirstlane(cntv.x);
      const int ns1 = __builtin_amdgcn_readfirstlane(cntv.y);
      const int ns2 = __builtin_amdgcn_readfirstlane(cntv.z);
      const int m0 = (ns0 > 8) ? ((ns0 - 1) >> 3) : 0;   // remaining groups
      const int m1 = (ns1 > 8) ? ((ns1 - 1) >> 3) : 0;
      const int m2 = (ns2 > 8) ? ((ns2 - 1) >> 3) : 0;
      const int M  = m0 + m1 + m2;
      auto vbase = [&](int g) -> const char* {           // pure SGPR cselects
        const int r1 = g - m0, r2 = g - m0 - m1;
        const int off = (g < m0) ? (32 + (g << 5))
                      : (r1 < m1) ? (SEGB + 32 + (r1 << 5))
                      : (2 * SEGB + 32 + (r2 << 5));
        return l0r + off;
      };

      int4 e0a,e0b,e1a,e1b,e2a,e2b,e3a,e3b;
      if (M > 0) READC(e0a, e0b, vbase(0), 0);           // all index reads first
      if (M > 1) READC(e1a, e1b, vbase(1), 0);
      if (M > 2) READC(e2a, e2b, vbase(2), 0);
      if (M > 3) READC(e3a, e3b, vbase(3), 0);
      CONS8F(a0, hA);
      CONS8F(a0, hB);
      CONS8F(a0, hC);
      if (M > 0) ISS8L0(hA, e0a, e0b);
      if (M > 1) ISS8L0(hB, e1a, e1b);
      if (M > 2) ISS8L0(hC, e2a, e2b);
      if (M > 3) ISS8L0(hD, e3a, e3b);
      if (M > 0) CONS8F(a0, hA);
      if (M > 1) CONS8F(a0, hB);
      if (M > 2) CONS8F(a0, hC);
      if (M > 3) CONS8F(a0, hD);
      if (M > 4) {                                       // overflow, rare
        #pragma unroll 1
        for (int g = 4; g < M; ++g) {
          int4 ea, eb;
          READC(ea, eb, vbase(g), 0);
          ISS8L0(hD, ea, eb);
          CONS8F(a0, hD);
        }
      }

      // LIF layer 0 (1 neuron/lane, exact reference op order)
      const float aa = z + a0;
      v0 = v0 + (aa - v0) * 0.5f;
      const bool s = (v0 >= 1.0f);
      const unsigned long long m = __ballot(s ? 1 : 0);
      if (s) v0 = 0.0f;
      // publish s0(t)
      *(float*)(lds + LDS_S0 + wp * 768 + nn4) = s ? 1.0f : 0.0f;
      // compact segment list for step t+1
      char* l0w = lds + LDS_LIST0 + wp * 864 + wv * SEGB;
      if (s) *(int*)(l0w + 4 * lanecnt_lt(m)) = tid * ROWB;
      const int pc = (int)__popcll(m);
      if (ln < 8) *(int*)(l0w + 4 * (pc + ln)) = L0_PAD;
      if (ln == 0) *(int*)(lds + LDS_CNT + wp * 16 + wv * 4) = pc;
    }

    __syncthreads();   // s0/list0/counts(t) published

    if (isW0) {
      // ============ prefetch for next step ============
      l0r = lds + LDS_LIST0 + wp * 864;
      cntv = *(const int4*)(lds + LDS_CNT + wp * 16);
      READC(p0a, p0b, l0r, 0);
      READC(p1a, p1b, l0r + SEGB, 0);
      READC(p2a, p2b, l0r + 2 * SEGB, 0);
      const int tn = (t + 1 < TT) ? t + 1 : 0;
      x0 = xb[tn * 3 + 0]; x1 = xb[tn * 3 + 1]; x2 = xb[tn * 3 + 2];
    } else {
      // ================= wave 3: layer 1 =================
      const char* s0r = lds + LDS_S0 + wp * 768;
      const float s0x = *(const float*)(s0r + ln12 + 0);
      const float s0y = *(const float*)(s0r + ln12 + 4);
      const float s0z = *(const float*)(s0r + ln12 + 8);
      // consume W1 gather issued last step (full step of flight time)
      float a1x = 0.f, a1y = 0.f, a1z = 0.f;
      if (ngl > 0) CONS8V3(gA);
      if (ngl > 1) CONS8V3(gB);
      if (ngl > 2) CONS8V3(gC);
      if (ngl > 3) CONS8V3(gD);
      if (ngl > 4) {                                  // overflow (>32 spikes)
        #pragma unroll 1
        for (int og = 4; og < ngl; ++og) {
          int4 ea, eb;
          READC(ea, eb, list1b, og);
          F3 r0,r1,r2,r3,r4,r5,r6,r7;
          ISS8W1(r, ea, eb);
          a1x += ((((r0).x+(r1).x)+((r2).x+(r3).x))+(((r4).x+(r5).x)+((r6).x+(r7).x)));
          a1y += ((((r0).y+(r1).y)+((r2).y+(r3).y))+(((r4).y+(r5).y)+((r6).y+(r7).y)));
          a1z += ((((r0).z+(r1).z)+((r2).z+(r3).z))+(((r4).z+(r5).z)+((r6).z+(r7).z)));
        }
      }
      // LIF layer 1: 3 independent neurons, positions from SALU popc prefixes
      const float u0 = b1z0 + (a1x + s0x);
      v10 = v10 + (u0 - v10) * 0.5f;
      const bool sA = (v10 >= 1.0f);
      const float u1 = b1z1 + (a1y + s0y);
      v11 = v11 + (u1 - v11) * 0.5f;
      const bool sB = (v11 >= 1.0f);
      const float u2 = b1z2 + (a1z + s0z);
      v12 = v12 + (u2 - v12) * 0.5f;
      const bool sC = (v12 >= 1.0f);
      const unsigned long long mA = __ballot(sA ? 1 : 0);
      const unsigned long long mB = __ballot(sB ? 1 : 0);
      const unsigned long long mC = __ballot(sC ? 1 : 0);
      const int cA  = (int)__popcll(mA);
      const int cAB = cA + (int)__popcll(mB);
      const int p   = cAB + (int)__popcll(mC);
      if (sA) { v10 = 0.0f; cnt0 += 1.0f;
                *(int*)(list1b + 4 * lanecnt_lt(mA)) = vo10; }
      if (sB) { v11 = 0.0f; cnt1 += 1.0f;
                *(int*)(list1b + 4 * (cA + lanecnt_lt(mB))) = vo11; }
      if (sC) { v12 = 0.0f; cnt2 += 1.0f;
                *(int*)(list1b + 4 * (cAB + lanecnt_lt(mC))) = vo12; }
      if (ln < 8) *(int*)(list1b + 4 * (p + ln)) = 0;  // pads -> zero row
      const int ng1 = (p + 7) >> 3;
      int4 d0a,d0b,d1a,d1b,d2a,d2b,d3a,d3b;
      READC(d0a, d0b, list1b, 0);
      READC(d1a, d1b, list1b, 1);
      READC(d2a, d2b, list1b, 2);
      READC(d3a, d3b, list1b, 3);
      if (ng1 > 0) ISS8W1(gA, d0a, d0b);               // fly across next step
      if (ng1 > 1) ISS8W1(gB, d1a, d1b);
      if (ng1 > 2) ISS8W1(gC, d2a, d2b);
      if (ng1 > 3) ISS8W1(gD, d3a, d3b);
      ngl = ng1;
    }
  }

  // ---- epilogue: exact mean (count * 2^-11) + head GEMV ----
  if (wv == 3) {
    const float r = 1.0f / 2048.0f;
    *(float*)((char*)feat + ln12 + 0) = cnt0 * r;
    *(float*)((char*)feat + ln12 + 4) = cnt1 * r;
    *(float*)((char*)feat + ln12 + 8) = cnt2 * r;
  }
  __syncthreads();
  if (tid < NCLS) {
    float a = b_head[tid];
    const float* wh = W_head + tid * HN;
    #pragma unroll 8
    for (int q = 0; q < HN; ++q) a += feat[q] * wh[q];
    out[b * NCLS + tid] = a;
  }
}

extern "C" void kernel_launch(void* const* d_in, const int* in_sizes, int n_in,
                              void* d_out, int out_size, void* d_ws, size_t ws_size,
                              hipStream_t stream) {
  const float* x       = (const float*)d_in[0];
  const float* W_in    = (const float*)d_in[1];
  const float* b_in    = (const float*)d_in[2];
  const float* W_cells = (const float*)d_in[3];
  const float* b_cells = (const float*)d_in[4];
  const float* W_head  = (const float*)d_in[5];
  const float* b_head  = (const float*)d_in[6];
  float* out = (float*)d_out;
  float* ws  = (float*)d_ws;   // 296704 bytes used

  snn_pack_k<<<(2 * HN * HN + 512 + 255) / 256, 256, 0, stream>>>(W_cells, ws);
  snn_main_k<<<128, 256, LDS_TOTAL, stream>>>(
      x, W_in, b_in, b_cells, W_head, b_head, ws, out);
}

// Round 8
// 1400.694 us; speedup vs baseline: 1.0665x; 1.0665x over previous
//
#include <hip/hip_runtime.h>

#define HN 192
#define TT 2048
#define NCLS 12
#define ROWB 768
// LDS layout (bytes)
#define L0_PAD    147456           // 2048B zero region (pad reads land here)
#define LDS_LIST0 149504           // 928B spike list, layer 0
#define LDS_LIST1 150432           // 928B spike list, layer 1
#define LDS_FEAT  151360           // 768B
#define LDS_TOTAL 152128

// ws layout (floats): [w0 rows 0..191][zero row][w1 rows 0..191][1024B pad]
__global__ void snn_pack_k(const float* __restrict__ Wc, float* __restrict__ ws) {
  int idx = blockIdx.x * 256 + threadIdx.x;
  if (idx < HN * HN) {                       // layer 0: Wc[0][i][j] -> ws[j*192+i]
    int i = idx / HN, j = idx % HN;
    ws[j * HN + i] = Wc[idx];
  } else if (idx < 2 * HN * HN) {            // layer 1 -> rows 193..384
    int r = idx - HN * HN;
    int i = r / HN, j = r % HN;
    ws[(193 + j) * HN + i] = Wc[idx];
  } else {
    int r = idx - 2 * HN * HN;
    if (r < HN) ws[192 * HN + r] = 0.0f;     // zero row
    if (r < 256) ws[385 * HN + r] = 0.0f;    // tail pad (1024B)
  }
}

__device__ __forceinline__ float4 add4(float4 a, float4 b) {
  return make_float4(a.x + b.x, a.y + b.y, a.z + b.z, a.w + b.w);
}
__device__ __forceinline__ int lanecnt_lt(unsigned long long m) {
  return __builtin_amdgcn_mbcnt_hi((unsigned)(m >> 32),
           __builtin_amdgcn_mbcnt_lo((unsigned)m, 0u));
}

#define READC(da, db, base, c) do { \
  da = *(const int4*)((base) + (c) * 32); \
  db = *(const int4*)((base) + (c) * 32 + 16); } while (0)

#define ISS8Q(p, ca, cb, basep) do { \
  p##0 = *(const float4*)((basep) + (unsigned)(ca).x + ln16); \
  p##1 = *(const float4*)((basep) + (unsigned)(ca).y + ln16); \
  p##2 = *(const float4*)((basep) + (unsigned)(ca).z + ln16); \
  p##3 = *(const float4*)((basep) + (unsigned)(ca).w + ln16); \
  p##4 = *(const float4*)((basep) + (unsigned)(cb).x + ln16); \
  p##5 = *(const float4*)((basep) + (unsigned)(cb).y + ln16); \
  p##6 = *(const float4*)((basep) + (unsigned)(cb).z + ln16); \
  p##7 = *(const float4*)((basep) + (unsigned)(cb).w + ln16); } while (0)

#define CONS8Q(acc, p) acc = add4(acc, \
  add4(add4(add4(p##0, p##1), add4(p##2, p##3)), \
       add4(add4(p##4, p##5), add4(p##6, p##7))))

// ONE wave per batch. Lane ln owns neurons 4ln..4ln+3 of BOTH layers
// (lanes 48-63 parked): s0 -> L1 handoff is in-register; spike counts in
// SGPRs; no barriers in the scan. List-read turnaround hidden by phase
// interleave; L1 global gather gets a full iteration of flight time.
__global__ __launch_bounds__(128, 1) void snn_main_k(
    const float* __restrict__ x, const float* __restrict__ W_in,
    const float* __restrict__ b_in, const float* __restrict__ b_cells,
    const float* __restrict__ W_head, const float* __restrict__ b_head,
    const float* __restrict__ ws, float* __restrict__ out)
{
  extern __shared__ char lds[];
  const int tid = threadIdx.x;
  const int ln  = tid & 63;
  const int b   = blockIdx.x;
  const unsigned ln16 = (unsigned)ln << 4;
  const char* ldsb = lds;
  char* list0b = lds + LDS_LIST0;
  char* list1b = lds + LDS_LIST1;
  float* feat  = (float*)(lds + LDS_FEAT);
  const char* w1zb = (const char*)ws + 192 * ROWB;   // zero row = L1 offset base

  // stage W0 (9216 float4) + 2048B zero guard — both waves help, wave1 exits
  {
    const float4* src = (const float4*)ws;
    float4* dst = (float4*)lds;
    for (int i = tid; i < (192 * ROWB) / 16; i += 128) dst[i] = src[i];
    float4 z4 = make_float4(0.f, 0.f, 0.f, 0.f);
    ((float4*)(lds + L0_PAD))[tid] = z4;             // 128 * 16B = 2048B
  }
  __syncthreads();
  if (tid >= 64) return;                             // single wave from here on

  // per-lane constants: 4 neurons/lane, lanes 0-47 active
  float wi0[4], wi1[4], wi2[4], zb[4], b1z[4];
  #pragma unroll
  for (int k = 0; k < 4; ++k) {
    int i = 4 * ln + k;
    bool a = (i < HN);
    int ii = a ? i : 0;
    wi0[k] = a ? W_in[ii * 3 + 0] : 0.f;
    wi1[k] = a ? W_in[ii * 3 + 1] : 0.f;
    wi2[k] = a ? W_in[ii * 3 + 2] : 0.f;
    zb[k]  = a ? (b_in[ii] + b_cells[ii]) : -1e30f;  // park idle lanes
    b1z[k] = a ? b_cells[HN + ii] : -1e30f;
  }
  const float* __restrict__ xb = x + (size_t)b * TT * 3;
  const int vo = ln * 3072;                          // own column-group base

  float v0k[4] = {0, 0, 0, 0}, v1k[4] = {0, 0, 0, 0}, cntk[4] = {0, 0, 0, 0};
  int n0 = 0, ngl = 0;
  int4 c0a = {0,0,0,0}, c0b = {0,0,0,0}, c1a = {0,0,0,0}, c1b = {0,0,0,0};
  float4 gA0, gA1, gA2, gA3, gA4, gA5, gA6, gA7;
  float4 gB0, gB1, gB2, gB3, gB4, gB5, gB6, gB7;
  gA0=gA1=gA2=gA3=gA4=gA5=gA6=gA7=make_float4(0.f,0.f,0.f,0.f);
  gB0=gB1=gB2=gB3=gB4=gB5=gB6=gB7=gA0;
  float x0 = xb[0], x1 = xb[1], x2 = xb[2];

  #pragma unroll 1
  for (int t = 0; t < TT; ++t) {
    // ---- 1: input projection (carried x) + next-x prefetch ----
    float zarr[4];
    #pragma unroll
    for (int k = 0; k < 4; ++k)
      zarr[k] = x0 * wi0[k] + x1 * wi1[k] + x2 * wi2[k] + zb[k];
    const int tn = (t + 1 < TT) ? t + 1 : 0;
    const float nx0 = xb[tn * 3 + 0], nx1 = xb[tn * 3 + 1], nx2 = xb[tn * 3 + 2];

    // ---- 2: L0 gather (chunks c* prefetched late last iter -> hidden) ----
    const int ngr0 = (n0 + 7) >> 3;
    float4 a0v = make_float4(0.f, 0.f, 0.f, 0.f);
    {
      float4 hA0, hA1, hA2, hA3, hA4, hA5, hA6, hA7;
      float4 hB0, hB1, hB2, hB3, hB4, hB5, hB6, hB7;
      if (ngr0 > 0) ISS8Q(hA, c0a, c0b, ldsb);
      if (ngr0 > 1) ISS8Q(hB, c1a, c1b, ldsb);
      if (ngr0 > 0) CONS8Q(a0v, hA);
      if (ngr0 > 1) CONS8Q(a0v, hB);
      if (ngr0 > 2) {                                // rare overflow
        #pragma unroll 1
        for (int g = 2; g < ngr0; ++g) {
          int4 ea, eb;
          READC(ea, eb, list0b, g);
          float4 r0, r1, r2, r3, r4, r5, r6, r7;
          ISS8Q(r, ea, eb, ldsb);
          CONS8Q(a0v, r);
        }
      }
    }

    // ---- 3: LIF layer 0 (flattened; exact reference op order) ----
    const float a0arr[4] = {a0v.x, a0v.y, a0v.z, a0v.w};
    float s0f[4];
    unsigned long long mm0, mm1, mm2, mm3;
    {
      float aa, v;
      aa = zarr[0] + a0arr[0]; v = v0k[0] + (aa - v0k[0]) * 0.5f;
      bool s0 = (v >= 1.0f); mm0 = __ballot(s0 ? 1 : 0);
      s0f[0] = s0 ? 1.0f : 0.0f; v0k[0] = s0 ? 0.0f : v;
      aa = zarr[1] + a0arr[1]; v = v0k[1] + (aa - v0k[1]) * 0.5f;
      bool s1 = (v >= 1.0f); mm1 = __ballot(s1 ? 1 : 0);
      s0f[1] = s1 ? 1.0f : 0.0f; v0k[1] = s1 ? 0.0f : v;
      aa = zarr[2] + a0arr[2]; v = v0k[2] + (aa - v0k[2]) * 0.5f;
      bool s2 = (v >= 1.0f); mm2 = __ballot(s2 ? 1 : 0);
      s0f[2] = s2 ? 1.0f : 0.0f; v0k[2] = s2 ? 0.0f : v;
      aa = zarr[3] + a0arr[3]; v = v0k[3] + (aa - v0k[3]) * 0.5f;
      bool s3 = (v >= 1.0f); mm3 = __ballot(s3 ? 1 : 0);
      s0f[3] = s3 ? 1.0f : 0.0f; v0k[3] = s3 ? 0.0f : v;
    }
    // ---- 4: compact list0 + pads ----
    const int q0   = (int)__popcll(mm0);
    const int q01  = q0  + (int)__popcll(mm1);
    const int q012 = q01 + (int)__popcll(mm2);
    const int p0n  = q012 + (int)__popcll(mm3);
    if (s0f[0] != 0.f) *(int*)(list0b + 4 * lanecnt_lt(mm0)) = vo;
    if (s0f[1] != 0.f) *(int*)(list0b + 4 * (q0   + lanecnt_lt(mm1))) = vo + ROWB;
    if (s0f[2] != 0.f) *(int*)(list0b + 4 * (q01  + lanecnt_lt(mm2))) = vo + 2 * ROWB;
    if (s0f[3] != 0.f) *(int*)(list0b + 4 * (q012 + lanecnt_lt(mm3))) = vo + 3 * ROWB;
    if (ln < 8) *(int*)(list0b + 4 * (p0n + ln)) = L0_PAD;
    // ---- 5: prefetch list0 chunks (needed next iter -> hidden by L1 phase) ----
    READC(c0a, c0b, list0b, 0);
    READC(c1a, c1b, list0b, 1);

    // ---- 6: L1 consume (globals issued last iter, full flight time) ----
    float4 a1v = make_float4(0.f, 0.f, 0.f, 0.f);
    if (ngl > 0) CONS8Q(a1v, gA);
    if (ngl > 1) CONS8Q(a1v, gB);
    if (ngl > 2) {                                   // rare overflow
      #pragma unroll 1
      for (int og = 2; og < ngl; ++og) {
        int4 ea, eb;
        READC(ea, eb, list1b, og);
        float4 r0, r1, r2, r3, r4, r5, r6, r7;
        ISS8Q(r, ea, eb, w1zb);
        CONS8Q(a1v, r);
      }
    }

    // ---- 7: LIF layer 1 (s0 handoff in-register) ----
    const float a1arr[4] = {a1v.x, a1v.y, a1v.z, a1v.w};
    unsigned long long nn0, nn1, nn2, nn3;
    float s1w[4];
    {
      float u, v;
      u = b1z[0] + a1arr[0] + s0f[0]; v = v1k[0] + (u - v1k[0]) * 0.5f;
      bool s0 = (v >= 1.0f); nn0 = __ballot(s0 ? 1 : 0);
      s1w[0] = s0 ? 1.0f : 0.0f; v1k[0] = s0 ? 0.0f : v;
      u = b1z[1] + a1arr[1] + s0f[1]; v = v1k[1] + (u - v1k[1]) * 0.5f;
      bool s1 = (v >= 1.0f); nn1 = __ballot(s1 ? 1 : 0);
      s1w[1] = s1 ? 1.0f : 0.0f; v1k[1] = s1 ? 0.0f : v;
      u = b1z[2] + a1arr[2] + s0f[2]; v = v1k[2] + (u - v1k[2]) * 0.5f;
      bool s2 = (v >= 1.0f); nn2 = __ballot(s2 ? 1 : 0);
      s1w[2] = s2 ? 1.0f : 0.0f; v1k[2] = s2 ? 0.0f : v;
      u = b1z[3] + a1arr[3] + s0f[3]; v = v1k[3] + (u - v1k[3]) * 0.5f;
      bool s3 = (v >= 1.0f); nn3 = __ballot(s3 ? 1 : 0);
      s1w[3] = s3 ? 1.0f : 0.0f; v1k[3] = s3 ? 0.0f : v;
    }
    cntk[0] += s1w[0]; cntk[1] += s1w[1]; cntk[2] += s1w[2]; cntk[3] += s1w[3];
    // ---- 8: compact list1 + pads ----
    const int r0c  = (int)__popcll(nn0);
    const int r01  = r0c + (int)__popcll(nn1);
    const int r012 = r01 + (int)__popcll(nn2);
    const int p1n  = r012 + (int)__popcll(nn3);
    if (s1w[0] != 0.f) *(int*)(list1b + 4 * lanecnt_lt(nn0)) = vo + ROWB;
    if (s1w[1] != 0.f) *(int*)(list1b + 4 * (r0c  + lanecnt_lt(nn1))) = vo + 2 * ROWB;
    if (s1w[2] != 0.f) *(int*)(list1b + 4 * (r01  + lanecnt_lt(nn2))) = vo + 3 * ROWB;
    if (s1w[3] != 0.f) *(int*)(list1b + 4 * (r012 + lanecnt_lt(nn3))) = vo + 4 * ROWB;
    if (ln < 8) *(int*)(list1b + 4 * (p1n + ln)) = 0;     // pads -> zero row
    // ---- 9/10: read list1 chunks, issue next L1 gather (flies a full iter) ----
    {
      int4 d0a, d0b, d1a, d1b;
      READC(d0a, d0b, list1b, 0);
      READC(d1a, d1b, list1b, 1);
      const int ng1 = (p1n + 7) >> 3;
      if (ng1 > 0) ISS8Q(gA, d0a, d0b, w1zb);
      if (ng1 > 1) ISS8Q(gB, d1a, d1b, w1zb);
      ngl = ng1;
    }

    n0 = p0n;
    x0 = nx0; x1 = nx1; x2 = nx2;
  }

  // ---- epilogue: exact mean (count * 2^-11) + head GEMV (same wave) ----
  if (ln < 48) {
    const float r = 1.0f / 2048.0f;
    ((float4*)feat)[ln] = make_float4(cntk[0] * r, cntk[1] * r, cntk[2] * r, cntk[3] * r);
  }
  if (ln < NCLS) {
    float a = b_head[ln];
    const float* wh = W_head + ln * HN;
    #pragma unroll 8
    for (int q = 0; q < HN; ++q) a += feat[q] * wh[q];
    out[b * NCLS + ln] = a;
  }
}

extern "C" void kernel_launch(void* const* d_in, const int* in_sizes, int n_in,
                              void* d_out, int out_size, void* d_ws, size_t ws_size,
                              hipStream_t stream) {
  const float* x       = (const float*)d_in[0];
  const float* W_in    = (const float*)d_in[1];
  const float* b_in    = (const float*)d_in[2];
  const float* W_cells = (const float*)d_in[3];
  const float* b_cells = (const float*)d_in[4];
  const float* W_head  = (const float*)d_in[5];
  const float* b_head  = (const float*)d_in[6];
  float* out = (float*)d_out;
  float* ws  = (float*)d_ws;   // 296704 bytes used

  snn_pack_k<<<(2 * HN * HN + 512 + 255) / 256, 256, 0, stream>>>(W_cells, ws);
  snn_main_k<<<128, 128, LDS_TOTAL, stream>>>(
      x, W_in, b_in, b_cells, W_head, b_head, ws, out);
}

// Round 9
// 1023.863 us; speedup vs baseline: 1.4590x; 1.3680x over previous
//
#include <hip/hip_runtime.h>

#define HN 192
#define TT 2048
#define NCLS 12
#define ROWB 768
// LDS layout (bytes)
#define L0_PAD    147456           // 2048B zero region (pad reads land here)
#define LDS_LIST0 149504           // 928B spike list, layer 0 (wave0-private)
#define LDS_LIST1 150432           // 928B spike list, layer 1 (wave1-private)
#define LDS_S0    151360           // 2 x 768B s0 double buffer (parity)
#define LDS_FEAT  152896           // 768B
#define LDS_TOTAL 153664

// ws layout (floats): [w0 rows 0..191][zero row][w1 rows 0..191][1024B pad]
__global__ void snn_pack_k(const float* __restrict__ Wc, float* __restrict__ ws) {
  int idx = blockIdx.x * 256 + threadIdx.x;
  if (idx < HN * HN) {                       // layer 0: Wc[0][i][j] -> ws[j*192+i]
    int i = idx / HN, j = idx % HN;
    ws[j * HN + i] = Wc[idx];
  } else if (idx < 2 * HN * HN) {            // layer 1 -> rows 193..384
    int r = idx - HN * HN;
    int i = r / HN, j = r % HN;
    ws[(193 + j) * HN + i] = Wc[idx];
  } else {
    int r = idx - 2 * HN * HN;
    if (r < HN) ws[192 * HN + r] = 0.0f;     // zero row
    if (r < 256) ws[385 * HN + r] = 0.0f;    // tail pad
  }
}

__device__ __forceinline__ float4 add4(float4 a, float4 b) {
  return make_float4(a.x + b.x, a.y + b.y, a.z + b.z, a.w + b.w);
}
__device__ __forceinline__ int lanecnt_lt(unsigned long long m) {
  return __builtin_amdgcn_mbcnt_hi((unsigned)(m >> 32),
           __builtin_amdgcn_mbcnt_lo((unsigned)m, 0u));
}

#define READC(da, db, base, c) do { \
  da = *(const int4*)((base) + (c) * 32); \
  db = *(const int4*)((base) + (c) * 32 + 16); } while (0)

#define ISS8Q(p, ca, cb, basep) do { \
  p##0 = *(const float4*)((basep) + (unsigned)(ca).x + ln16); \
  p##1 = *(const float4*)((basep) + (unsigned)(ca).y + ln16); \
  p##2 = *(const float4*)((basep) + (unsigned)(ca).z + ln16); \
  p##3 = *(const float4*)((basep) + (unsigned)(ca).w + ln16); \
  p##4 = *(const float4*)((basep) + (unsigned)(cb).x + ln16); \
  p##5 = *(const float4*)((basep) + (unsigned)(cb).y + ln16); \
  p##6 = *(const float4*)((basep) + (unsigned)(cb).z + ln16); \
  p##7 = *(const float4*)((basep) + (unsigned)(cb).w + ln16); } while (0)

#define CONS8Q(acc, p) acc = add4(acc, \
  add4(add4(add4(p##0, p##1), add4(p##2, p##3)), \
       add4(add4(p##4, p##5), add4(p##6, p##7))))

// 2 waves per batch, one-step-lagged pipeline:
//   wave0 at iteration i runs layer-0 step i (LDS weights), publishes s0(i).
//   wave1 at iteration i runs layer-1 step i-1 (global W1 gather issued at the
//   end of iteration i-1 -> real flight), reads s0(i-1) -- one barrier after
//   its publish, so a single raw s_barrier per iteration suffices.
// Manual partial s_waitcnt lgkmcnt(4) on wave0 (DS completes in-order; only
// its own 4 list-chunk reads may remain outstanding at the barrier).
__global__ __launch_bounds__(128, 1) void snn_main_k(
    const float* __restrict__ x, const float* __restrict__ W_in,
    const float* __restrict__ b_in, const float* __restrict__ b_cells,
    const float* __restrict__ W_head, const float* __restrict__ b_head,
    const float* __restrict__ ws, float* __restrict__ out)
{
  extern __shared__ char lds[];
  const int tid = threadIdx.x;
  const int ln  = tid & 63;
  const bool isW0 = (tid < 64);
  const int b   = blockIdx.x;
  const unsigned ln16 = (unsigned)ln << 4;
  const char* ldsb = lds;
  char* list0b = lds + LDS_LIST0;
  char* list1b = lds + LDS_LIST1;
  float* feat  = (float*)(lds + LDS_FEAT);
  const char* w1zb = (const char*)ws + 192 * ROWB;   // zero row = L1 offset base

  // stage W0 (9216 float4) + 2048B zero guard (both waves)
  {
    const float4* src = (const float4*)ws;
    float4* dst = (float4*)lds;
    for (int i = tid; i < (192 * ROWB) / 16; i += 128) dst[i] = src[i];
    ((float4*)(lds + L0_PAD))[tid] = make_float4(0.f, 0.f, 0.f, 0.f);
  }
  __syncthreads();

  // opaque zero: forces x loads to VMEM (global_load, vmcnt) -- keeps the
  // lgkm counter purely DS so the manual lgkmcnt(4) count is exact.
  int vz;
  asm volatile("v_mov_b32 %0, 0" : "=v"(vz));

  // per-lane constants (4 neurons/lane in both layers; lanes 48-63 parked)
  float wi0[4], wi1[4], wi2[4], zb[4], b1z[4];
  #pragma unroll
  for (int k = 0; k < 4; ++k) {
    int i = 4 * ln + k;
    bool a = (i < HN);
    int ii = a ? i : 0;
    wi0[k] = a ? W_in[ii * 3 + 0] : 0.f;
    wi1[k] = a ? W_in[ii * 3 + 1] : 0.f;
    wi2[k] = a ? W_in[ii * 3 + 2] : 0.f;
    zb[k]  = a ? (b_in[ii] + b_cells[ii]) : -1e30f;
    b1z[k] = a ? b_cells[HN + ii] : -1e30f;
  }
  const float* __restrict__ xb = x + (size_t)b * TT * 3;
  const int vo = ln * 3072;

  // wave0 state
  float v0k[4] = {0, 0, 0, 0};
  int n0 = 0;
  int4 c0a = {0,0,0,0}, c0b = {0,0,0,0}, c1a = {0,0,0,0}, c1b = {0,0,0,0};
  float x0 = xb[vz + 0], x1 = xb[vz + 1], x2 = xb[vz + 2];
  // wave1 state
  float v1k[4] = {0, 0, 0, 0}, cntk[4] = {0, 0, 0, 0};
  int ngl = 0;
  float4 gA0, gA1, gA2, gA3, gA4, gA5, gA6, gA7;
  float4 gB0, gB1, gB2, gB3, gB4, gB5, gB6, gB7;
  gA0=gA1=gA2=gA3=gA4=gA5=gA6=gA7=make_float4(0.f,0.f,0.f,0.f);
  gB0=gB1=gB2=gB3=gB4=gB5=gB6=gB7=gA0;

  #pragma unroll 1
  for (int i = 0; i <= TT; ++i) {
    if (isW0) {
      if (i < TT) {
        // ======== wave 0: layer-0 step i ========
        const int wp = i & 1;
        // gather: issue first (chunks read at end of previous block)
        const int ngr0 = (n0 + 7) >> 3;
        float4 a0v = make_float4(0.f, 0.f, 0.f, 0.f);
        float4 hA0, hA1, hA2, hA3, hA4, hA5, hA6, hA7;
        float4 hB0, hB1, hB2, hB3, hB4, hB5, hB6, hB7;
        if (ngr0 > 0) ISS8Q(hA, c0a, c0b, ldsb);
        if (ngr0 > 1) ISS8Q(hB, c1a, c1b, ldsb);
        // input projection (carried x) + next-x prefetch (VMEM, in flight)
        float zh[4];
        #pragma unroll
        for (int k = 0; k < 4; ++k)
          zh[k] = (x0 * wi0[k] + x1 * wi1[k] + x2 * wi2[k] + zb[k]) * 0.5f
                + v0k[k] * 0.5f;              // v/2 + (z-part)/2, a0 added below
        const int tn = (i + 1 < TT) ? i + 1 : 0;
        const float nx0 = xb[tn * 3 + vz + 0];
        const float nx1 = xb[tn * 3 + vz + 1];
        const float nx2 = xb[tn * 3 + vz + 2];
        if (ngr0 > 0) CONS8Q(a0v, hA);
        if (ngr0 > 1) CONS8Q(a0v, hB);
        if (ngr0 > 2) {                        // rare overflow
          #pragma unroll 1
          for (int g = 2; g < ngr0; ++g) {
            int4 ea, eb;
            READC(ea, eb, list0b, g);
            float4 r0, r1, r2, r3, r4, r5, r6, r7;
            ISS8Q(r, ea, eb, ldsb);
            CONS8Q(a0v, r);
          }
        }
        // LIF layer 0, flattened (v = v/2 + (z+a0)/2 — exact *0.5 arithmetic)
        const float a0arr[4] = {a0v.x, a0v.y, a0v.z, a0v.w};
        float s0f[4];
        unsigned long long mm0, mm1, mm2, mm3;
        {
          float v;
          v = zh[0] + a0arr[0] * 0.5f; bool s0 = (v >= 1.0f);
          mm0 = __ballot(s0 ? 1 : 0); s0f[0] = s0 ? 1.0f : 0.0f; v0k[0] = s0 ? 0.0f : v;
          v = zh[1] + a0arr[1] * 0.5f; bool s1 = (v >= 1.0f);
          mm1 = __ballot(s1 ? 1 : 0); s0f[1] = s1 ? 1.0f : 0.0f; v0k[1] = s1 ? 0.0f : v;
          v = zh[2] + a0arr[2] * 0.5f; bool s2 = (v >= 1.0f);
          mm2 = __ballot(s2 ? 1 : 0); s0f[2] = s2 ? 1.0f : 0.0f; v0k[2] = s2 ? 0.0f : v;
          v = zh[3] + a0arr[3] * 0.5f; bool s3 = (v >= 1.0f);
          mm3 = __ballot(s3 ? 1 : 0); s0f[3] = s3 ? 1.0f : 0.0f; v0k[3] = s3 ? 0.0f : v;
        }
        // publish s0(i) (parity buffer)
        if (ln < 48)
          *(float4*)(lds + LDS_S0 + wp * 768 + ln16) =
              make_float4(s0f[0], s0f[1], s0f[2], s0f[3]);
        // compact own list + pads
        const int q0   = (int)__popcll(mm0);
        const int q01  = q0  + (int)__popcll(mm1);
        const int q012 = q01 + (int)__popcll(mm2);
        const int p0n  = q012 + (int)__popcll(mm3);
        if (s0f[0] != 0.f) *(int*)(list0b + 4 * lanecnt_lt(mm0)) = vo;
        if (s0f[1] != 0.f) *(int*)(list0b + 4 * (q0   + lanecnt_lt(mm1))) = vo + ROWB;
        if (s0f[2] != 0.f) *(int*)(list0b + 4 * (q01  + lanecnt_lt(mm2))) = vo + 2 * ROWB;
        if (s0f[3] != 0.f) *(int*)(list0b + 4 * (q012 + lanecnt_lt(mm3))) = vo + 3 * ROWB;
        if (ln < 8) *(int*)(list0b + 4 * (p0n + ln)) = L0_PAD;
        n0 = p0n;
        asm volatile("" ::: "memory");         // writes issued before the reads
        READC(c0a, c0b, list0b, 0);
        READC(c1a, c1b, list0b, 1);
        // only the 4 chunk-reads may remain outstanding (DS is in-order):
        asm volatile("s_waitcnt lgkmcnt(4)" ::: "memory");
        x0 = nx0; x1 = nx1; x2 = nx2;
      }
    } else {
      if (i > 0) {
        // ======== wave 1: layer-1 step i-1 ========
        const int rp = (i - 1) & 1;
        // s0 read issued first; its wait overlaps the gather consume
        const float4 s0v = *(const float4*)(lds + LDS_S0 + rp * 768 + ln16);
        // consume W1 gather (issued at end of previous block -> real flight)
        float4 a1v = make_float4(0.f, 0.f, 0.f, 0.f);
        if (ngl > 0) CONS8Q(a1v, gA);
        if (ngl > 1) CONS8Q(a1v, gB);
        if (ngl > 2) {                         // rare overflow
          #pragma unroll 1
          for (int og = 2; og < ngl; ++og) {
            int4 ea, eb;
            READC(ea, eb, list1b, og);
            float4 r0, r1, r2, r3, r4, r5, r6, r7;
            ISS8Q(r, ea, eb, w1zb);
            CONS8Q(a1v, r);
          }
        }
        // LIF layer 1, flattened
        const float a1arr[4] = {a1v.x, a1v.y, a1v.z, a1v.w};
        const float s0a[4] = {s0v.x, s0v.y, s0v.z, s0v.w};
        float s1w[4];
        unsigned long long nn0, nn1, nn2, nn3;
        {
          float u, v;
          u = b1z[0] + a1arr[0] + s0a[0]; v = v1k[0] + (u - v1k[0]) * 0.5f;
          bool s0 = (v >= 1.0f); nn0 = __ballot(s0 ? 1 : 0);
          s1w[0] = s0 ? 1.0f : 0.0f; v1k[0] = s0 ? 0.0f : v;
          u = b1z[1] + a1arr[1] + s0a[1]; v = v1k[1] + (u - v1k[1]) * 0.5f;
          bool s1 = (v >= 1.0f); nn1 = __ballot(s1 ? 1 : 0);
          s1w[1] = s1 ? 1.0f : 0.0f; v1k[1] = s1 ? 0.0f : v;
          u = b1z[2] + a1arr[2] + s0a[2]; v = v1k[2] + (u - v1k[2]) * 0.5f;
          bool s2 = (v >= 1.0f); nn2 = __ballot(s2 ? 1 : 0);
          s1w[2] = s2 ? 1.0f : 0.0f; v1k[2] = s2 ? 0.0f : v;
          u = b1z[3] + a1arr[3] + s0a[3]; v = v1k[3] + (u - v1k[3]) * 0.5f;
          bool s3 = (v >= 1.0f); nn3 = __ballot(s3 ? 1 : 0);
          s1w[3] = s3 ? 1.0f : 0.0f; v1k[3] = s3 ? 0.0f : v;
        }
        cntk[0] += s1w[0]; cntk[1] += s1w[1]; cntk[2] += s1w[2]; cntk[3] += s1w[3];
        // compact own list + pads
        const int r0c  = (int)__popcll(nn0);
        const int r01  = r0c + (int)__popcll(nn1);
        const int r012 = r01 + (int)__popcll(nn2);
        const int p1n  = r012 + (int)__popcll(nn3);
        if (s1w[0] != 0.f) *(int*)(list1b + 4 * lanecnt_lt(nn0)) = vo + ROWB;
        if (s1w[1] != 0.f) *(int*)(list1b + 4 * (r0c  + lanecnt_lt(nn1))) = vo + 2 * ROWB;
        if (s1w[2] != 0.f) *(int*)(list1b + 4 * (r01  + lanecnt_lt(nn2))) = vo + 3 * ROWB;
        if (s1w[3] != 0.f) *(int*)(list1b + 4 * (r012 + lanecnt_lt(nn3))) = vo + 4 * ROWB;
        if (ln < 8) *(int*)(list1b + 4 * (p1n + ln)) = 0;   // pads -> zero row
        // read chunks + issue next gather (flight = tail + barrier + preamble)
        if (i < TT) {
          int4 d0a, d0b, d1a, d1b;
          READC(d0a, d0b, list1b, 0);
          READC(d1a, d1b, list1b, 1);
          const int ng1 = (p1n + 7) >> 3;
          if (ng1 > 0) ISS8Q(gA, d0a, d0b, w1zb);
          if (ng1 > 1) ISS8Q(gB, d1a, d1b, w1zb);
          ngl = ng1;
        }
      }
    }
    asm volatile("" ::: "memory");
    __builtin_amdgcn_s_barrier();
    __builtin_amdgcn_sched_barrier(0);
    asm volatile("" ::: "memory");
  }

  __syncthreads();
  // epilogue: exact mean (count * 2^-11) + head GEMV
  if (!isW0 && ln < 48) {
    const float r = 1.0f / 2048.0f;
    ((float4*)feat)[ln] = make_float4(cntk[0] * r, cntk[1] * r, cntk[2] * r, cntk[3] * r);
  }
  __syncthreads();
  if (tid < NCLS) {
    float a = b_head[tid];
    const float* wh = W_head + tid * HN;
    #pragma unroll 8
    for (int q = 0; q < HN; ++q) a += feat[q] * wh[q];
    out[b * NCLS + tid] = a;
  }
}

extern "C" void kernel_launch(void* const* d_in, const int* in_sizes, int n_in,
                              void* d_out, int out_size, void* d_ws, size_t ws_size,
                              hipStream_t stream) {
  const float* x       = (const float*)d_in[0];
  const float* W_in    = (const float*)d_in[1];
  const float* b_in    = (const float*)d_in[2];
  const float* W_cells = (const float*)d_in[3];
  const float* b_cells = (const float*)d_in[4];
  const float* W_head  = (const float*)d_in[5];
  const float* b_head  = (const float*)d_in[6];
  float* out = (float*)d_out;
  float* ws  = (float*)d_ws;   // 296704 bytes used

  snn_pack_k<<<(2 * HN * HN + 512 + 255) / 256, 256, 0, stream>>>(W_cells, ws);
  snn_main_k<<<128, 128, LDS_TOTAL, stream>>>(
      x, W_in, b_in, b_cells, W_head, b_head, ws, out);
}

// Round 10
// 891.492 us; speedup vs baseline: 1.6757x; 1.1485x over previous
//
#include <hip/hip_runtime.h>

#define HN 192
#define TT 2048
#define NCLS 12
#define ROWB 768
// LDS layout (bytes)
#define L0_PAD    147456           // 2048B zero region (pad reads land here)
#define LDS_LIST0 149504           // 1024B data slots + 256B junk
#define LDS_LIST1 150784           // same for layer 1
#define LDS_S0    152064           // 2 x 768B s0 double buffer (parity)
#define LDS_FEAT  153600           // 768B
#define LDS_TOTAL 154368

// ws layout (floats): [w0 rows 0..191][zero row][w1 rows 0..191][1024B pad]
__global__ void snn_pack_k(const float* __restrict__ Wc, float* __restrict__ ws) {
  int idx = blockIdx.x * 256 + threadIdx.x;
  if (idx < HN * HN) {                       // layer 0: Wc[0][i][j] -> ws[j*192+i]
    int i = idx / HN, j = idx % HN;
    ws[j * HN + i] = Wc[idx];
  } else if (idx < 2 * HN * HN) {            // layer 1 -> rows 193..384
    int r = idx - HN * HN;
    int i = r / HN, j = r % HN;
    ws[(193 + j) * HN + i] = Wc[idx];
  } else {
    int r = idx - 2 * HN * HN;
    if (r < HN) ws[192 * HN + r] = 0.0f;     // zero row
    if (r < 256) ws[385 * HN + r] = 0.0f;    // tail pad
  }
}

__device__ __forceinline__ float4 add4(float4 a, float4 b) {
  return make_float4(a.x + b.x, a.y + b.y, a.z + b.z, a.w + b.w);
}
__device__ __forceinline__ int lanecnt_lt(unsigned long long m) {
  return __builtin_amdgcn_mbcnt_hi((unsigned)(m >> 32),
           __builtin_amdgcn_mbcnt_lo((unsigned)m, 0u));
}

#define READC(da, db, base, c) do { \
  da = *(const int4*)((base) + (c) * 32); \
  db = *(const int4*)((base) + (c) * 32 + 16); } while (0)

#define ISS8Q(p, ca, cb, basep) do { \
  p##0 = *(const float4*)((basep) + (unsigned)(ca).x + ln16); \
  p##1 = *(const float4*)((basep) + (unsigned)(ca).y + ln16); \
  p##2 = *(const float4*)((basep) + (unsigned)(ca).z + ln16); \
  p##3 = *(const float4*)((basep) + (unsigned)(ca).w + ln16); \
  p##4 = *(const float4*)((basep) + (unsigned)(cb).x + ln16); \
  p##5 = *(const float4*)((basep) + (unsigned)(cb).y + ln16); \
  p##6 = *(const float4*)((basep) + (unsigned)(cb).z + ln16); \
  p##7 = *(const float4*)((basep) + (unsigned)(cb).w + ln16); } while (0)

#define CONS8Q(acc, p) acc = add4(acc, \
  add4(add4(add4(p##0, p##1), add4(p##2, p##3)), \
       add4(add4(p##4, p##5), add4(p##6, p##7))))

// 2 waves per batch, one-step-lagged pipeline (r9 skeleton), with branchless
// compaction (cndmask'd write addresses into a junk region), unconditional
// pad writes and unconditional group-0 issue/consume (pad-preset chunks).
__global__ __launch_bounds__(128, 1) void snn_main_k(
    const float* __restrict__ x, const float* __restrict__ W_in,
    const float* __restrict__ b_in, const float* __restrict__ b_cells,
    const float* __restrict__ W_head, const float* __restrict__ b_head,
    const float* __restrict__ ws, float* __restrict__ out)
{
  extern __shared__ char lds[];
  const int tid = threadIdx.x;
  const int ln  = tid & 63;
  const bool isW0 = (tid < 64);
  const int b   = blockIdx.x;
  const unsigned ln16 = (unsigned)ln << 4;
  const char* ldsb = lds;
  char* list0b = lds + LDS_LIST0;
  char* list1b = lds + LDS_LIST1;
  float* feat  = (float*)(lds + LDS_FEAT);
  const char* w1zb = (const char*)ws + 192 * ROWB;   // zero row = L1 offset base

  // stage W0 (9216 float4) + 2048B zero guard (both waves)
  {
    const float4* src = (const float4*)ws;
    float4* dst = (float4*)lds;
    for (int i = tid; i < (192 * ROWB) / 16; i += 128) dst[i] = src[i];
    ((float4*)(lds + L0_PAD))[tid] = make_float4(0.f, 0.f, 0.f, 0.f);
  }
  __syncthreads();

  // opaque zero: forces x loads to VMEM so lgkm counter stays purely DS
  int vz;
  asm volatile("v_mov_b32 %0, 0" : "=v"(vz));

  // per-lane constants (4 neurons/lane in both layers; lanes 48-63 parked)
  float wi0[4], wi1[4], wi2[4], zb[4], b1z[4];
  #pragma unroll
  for (int k = 0; k < 4; ++k) {
    int i = 4 * ln + k;
    bool a = (i < HN);
    int ii = a ? i : 0;
    wi0[k] = a ? W_in[ii * 3 + 0] : 0.f;
    wi1[k] = a ? W_in[ii * 3 + 1] : 0.f;
    wi2[k] = a ? W_in[ii * 3 + 2] : 0.f;
    zb[k]  = a ? (b_in[ii] + b_cells[ii]) : -1e30f;
    b1z[k] = a ? b_cells[HN + ii] : -1e30f;
  }
  const float* __restrict__ xb = x + (size_t)b * TT * 3;
  const int vo = ln * 3072;

  // wave0 state: chunks preset to pad offsets (iter0 gathers zeros)
  float v0k[4] = {0, 0, 0, 0};
  int n0 = 0;
  int4 c0a = {L0_PAD,L0_PAD,L0_PAD,L0_PAD}, c0b = c0a, c1a = c0a, c1b = c0a;
  float x0 = xb[vz + 0], x1 = xb[vz + 1], x2 = xb[vz + 2];
  // wave1 state
  float v1k[4] = {0, 0, 0, 0}, cntk[4] = {0, 0, 0, 0};
  int n1 = 0;
  float4 gA0, gA1, gA2, gA3, gA4, gA5, gA6, gA7;
  float4 gB0, gB1, gB2, gB3, gB4, gB5, gB6, gB7;
  if (!isW0) {
    // pre-loop: issue an initial pad gather (zero row) so iter1's consume is safe
    int4 dz = {0, 0, 0, 0};
    ISS8Q(gA, dz, dz, w1zb);
    gB0=gB1=gB2=gB3=gB4=gB5=gB6=gB7=make_float4(0.f,0.f,0.f,0.f);
  }

  #pragma unroll 1
  for (int i = 0; i <= TT; ++i) {
    if (isW0) {
      if (i < TT) {
        // ======== wave 0: layer-0 step i ========
        const int wp = i & 1;
        float4 a0v = make_float4(0.f, 0.f, 0.f, 0.f);
        float4 hA0, hA1, hA2, hA3, hA4, hA5, hA6, hA7;
        float4 hB0, hB1, hB2, hB3, hB4, hB5, hB6, hB7;
        ISS8Q(hA, c0a, c0b, ldsb);             // unconditional group 0
        if (n0 > 8) ISS8Q(hB, c1a, c1b, ldsb);
        // input projection (carried x) + next-x prefetch (VMEM, in flight)
        float zarr[4];
        #pragma unroll
        for (int k = 0; k < 4; ++k)
          zarr[k] = x0 * wi0[k] + x1 * wi1[k] + x2 * wi2[k] + zb[k];
        const int tn = (i + 1 < TT) ? i + 1 : 0;
        const float nx0 = xb[tn * 3 + vz + 0];
        const float nx1 = xb[tn * 3 + vz + 1];
        const float nx2 = xb[tn * 3 + vz + 2];
        CONS8Q(a0v, hA);
        if (n0 > 8) CONS8Q(a0v, hB);
        if (n0 > 16) {                          // rare overflow: chunks 2..3 + loop
          int4 e2a, e2b;
          float4 r0, r1, r2, r3, r4, r5, r6, r7;
          READC(e2a, e2b, list0b, 2);
          ISS8Q(r, e2a, e2b, ldsb);
          CONS8Q(a0v, r);
          if (n0 > 24) {
            READC(e2a, e2b, list0b, 3);
            ISS8Q(r, e2a, e2b, ldsb);
            CONS8Q(a0v, r);
          }
          if (n0 > 32) {
            #pragma unroll 1
            for (int g = 4; g * 8 < n0; ++g) {
              READC(e2a, e2b, list0b, g);
              ISS8Q(r, e2a, e2b, ldsb);
              CONS8Q(a0v, r);
            }
          }
        }
        // LIF layer 0 (exact reference op order), flattened
        const float a0arr[4] = {a0v.x, a0v.y, a0v.z, a0v.w};
        float s0f[4];
        bool sp[4];
        unsigned long long mm0, mm1, mm2, mm3;
        {
          float u, v;
          u = zarr[0] + a0arr[0]; v = v0k[0] + (u - v0k[0]) * 0.5f;
          sp[0] = (v >= 1.0f); mm0 = __ballot(sp[0] ? 1 : 0);
          s0f[0] = sp[0] ? 1.0f : 0.0f; v0k[0] = sp[0] ? 0.0f : v;
          u = zarr[1] + a0arr[1]; v = v0k[1] + (u - v0k[1]) * 0.5f;
          sp[1] = (v >= 1.0f); mm1 = __ballot(sp[1] ? 1 : 0);
          s0f[1] = sp[1] ? 1.0f : 0.0f; v0k[1] = sp[1] ? 0.0f : v;
          u = zarr[2] + a0arr[2]; v = v0k[2] + (u - v0k[2]) * 0.5f;
          sp[2] = (v >= 1.0f); mm2 = __ballot(sp[2] ? 1 : 0);
          s0f[2] = sp[2] ? 1.0f : 0.0f; v0k[2] = sp[2] ? 0.0f : v;
          u = zarr[3] + a0arr[3]; v = v0k[3] + (u - v0k[3]) * 0.5f;
          sp[3] = (v >= 1.0f); mm3 = __ballot(sp[3] ? 1 : 0);
          s0f[3] = sp[3] ? 1.0f : 0.0f; v0k[3] = sp[3] ? 0.0f : v;
        }
        // publish s0(i) (parity buffer)
        if (ln < 48)
          *(float4*)(lds + LDS_S0 + wp * 768 + ln16) =
              make_float4(s0f[0], s0f[1], s0f[2], s0f[3]);
        // branchless compaction: cndmask'd slot (junk slots at 256+ln)
        const int q0   = (int)__popcll(mm0);
        const int q01  = q0  + (int)__popcll(mm1);
        const int q012 = q01 + (int)__popcll(mm2);
        const int p0n  = q012 + (int)__popcll(mm3);
        const int jk = 256 + ln;
        {
          int s;
          s = sp[0] ? lanecnt_lt(mm0)          : jk; *(int*)(list0b + 4 * s) = vo;
          s = sp[1] ? (q0   + lanecnt_lt(mm1)) : jk; *(int*)(list0b + 4 * s) = vo + ROWB;
          s = sp[2] ? (q01  + lanecnt_lt(mm2)) : jk; *(int*)(list0b + 4 * s) = vo + 2 * ROWB;
          s = sp[3] ? (q012 + lanecnt_lt(mm3)) : jk; *(int*)(list0b + 4 * s) = vo + 3 * ROWB;
        }
        *(int*)(list0b + 4 * (p0n + ln)) = L0_PAD;   // unconditional pads
        n0 = p0n;
        asm volatile("" ::: "memory");
        READC(c0a, c0b, list0b, 0);
        READC(c1a, c1b, list0b, 1);
        // only the 4 chunk-reads may remain outstanding (DS is in-order):
        asm volatile("s_waitcnt lgkmcnt(4)" ::: "memory");
        x0 = nx0; x1 = nx1; x2 = nx2;
      }
    } else {
      if (i > 0) {
        // ======== wave 1: layer-1 step i-1 ========
        const int rp = (i - 1) & 1;
        const float4 s0v = *(const float4*)(lds + LDS_S0 + rp * 768 + ln16);
        // consume W1 gather (issued at end of previous block -> real flight)
        float4 a1v = make_float4(0.f, 0.f, 0.f, 0.f);
        CONS8Q(a1v, gA);                        // unconditional group 0
        if (n1 > 8) CONS8Q(a1v, gB);
        if (n1 > 16) {                          // rare overflow
          int4 e2a, e2b;
          float4 r0, r1, r2, r3, r4, r5, r6, r7;
          READC(e2a, e2b, list1b, 2);
          ISS8Q(r, e2a, e2b, w1zb);
          CONS8Q(a1v, r);
          if (n1 > 24) {
            READC(e2a, e2b, list1b, 3);
            ISS8Q(r, e2a, e2b, w1zb);
            CONS8Q(a1v, r);
          }
          if (n1 > 32) {
            #pragma unroll 1
            for (int g = 4; g * 8 < n1; ++g) {
              READC(e2a, e2b, list1b, g);
              ISS8Q(r, e2a, e2b, w1zb);
              CONS8Q(a1v, r);
            }
          }
        }
        // LIF layer 1, flattened
        const float a1arr[4] = {a1v.x + s0v.x, a1v.y + s0v.y,
                                a1v.z + s0v.z, a1v.w + s0v.w};
        float s1w[4];
        bool sq[4];
        unsigned long long nn0, nn1, nn2, nn3;
        {
          float u, v;
          u = b1z[0] + a1arr[0]; v = v1k[0] + (u - v1k[0]) * 0.5f;
          sq[0] = (v >= 1.0f); nn0 = __ballot(sq[0] ? 1 : 0);
          s1w[0] = sq[0] ? 1.0f : 0.0f; v1k[0] = sq[0] ? 0.0f : v;
          u = b1z[1] + a1arr[1]; v = v1k[1] + (u - v1k[1]) * 0.5f;
          sq[1] = (v >= 1.0f); nn1 = __ballot(sq[1] ? 1 : 0);
          s1w[1] = sq[1] ? 1.0f : 0.0f; v1k[1] = sq[1] ? 0.0f : v;
          u = b1z[2] + a1arr[2]; v = v1k[2] + (u - v1k[2]) * 0.5f;
          sq[2] = (v >= 1.0f); nn2 = __ballot(sq[2] ? 1 : 0);
          s1w[2] = sq[2] ? 1.0f : 0.0f; v1k[2] = sq[2] ? 0.0f : v;
          u = b1z[3] + a1arr[3]; v = v1k[3] + (u - v1k[3]) * 0.5f;
          sq[3] = (v >= 1.0f); nn3 = __ballot(sq[3] ? 1 : 0);
          s1w[3] = sq[3] ? 1.0f : 0.0f; v1k[3] = sq[3] ? 0.0f : v;
        }
        cntk[0] += s1w[0]; cntk[1] += s1w[1]; cntk[2] += s1w[2]; cntk[3] += s1w[3];
        // branchless compaction (junk slots at 256+ln; pad value 0 -> zero row)
        const int r0c  = (int)__popcll(nn0);
        const int r01  = r0c + (int)__popcll(nn1);
        const int r012 = r01 + (int)__popcll(nn2);
        const int p1n  = r012 + (int)__popcll(nn3);
        const int jk = 256 + ln;
        {
          int s;
          s = sq[0] ? lanecnt_lt(nn0)          : jk; *(int*)(list1b + 4 * s) = vo + ROWB;
          s = sq[1] ? (r0c  + lanecnt_lt(nn1)) : jk; *(int*)(list1b + 4 * s) = vo + 2 * ROWB;
          s = sq[2] ? (r01  + lanecnt_lt(nn2)) : jk; *(int*)(list1b + 4 * s) = vo + 3 * ROWB;
          s = sq[3] ? (r012 + lanecnt_lt(nn3)) : jk; *(int*)(list1b + 4 * s) = vo + 4 * ROWB;
        }
        *(int*)(list1b + 4 * (p1n + ln)) = 0;        // unconditional pads
        // read chunks + issue next gather (flight = tail + barrier + preamble)
        if (i < TT) {
          int4 d0a, d0b, d1a, d1b;
          asm volatile("" ::: "memory");
          READC(d0a, d0b, list1b, 0);
          READC(d1a, d1b, list1b, 1);
          ISS8Q(gA, d0a, d0b, w1zb);               // unconditional group 0
          if (p1n > 8) ISS8Q(gB, d1a, d1b, w1zb);
        }
        n1 = p1n;
      }
    }
    asm volatile("" ::: "memory");
    __builtin_amdgcn_s_barrier();
    __builtin_amdgcn_sched_barrier(0);
    asm volatile("" ::: "memory");
  }

  __syncthreads();
  // epilogue: exact mean (count * 2^-11) + head GEMV
  if (!isW0 && ln < 48) {
    const float r = 1.0f / 2048.0f;
    ((float4*)feat)[ln] = make_float4(cntk[0] * r, cntk[1] * r, cntk[2] * r, cntk[3] * r);
  }
  __syncthreads();
  if (tid < NCLS) {
    float a = b_head[tid];
    const float* wh = W_head + tid * HN;
    #pragma unroll 8
    for (int q = 0; q < HN; ++q) a += feat[q] * wh[q];
    out[b * NCLS + tid] = a;
  }
}

extern "C" void kernel_launch(void* const* d_in, const int* in_sizes, int n_in,
                              void* d_out, int out_size, void* d_ws, size_t ws_size,
                              hipStream_t stream) {
  const float* x       = (const float*)d_in[0];
  const float* W_in    = (const float*)d_in[1];
  const float* b_in    = (const float*)d_in[2];
  const float* W_cells = (const float*)d_in[3];
  const float* b_cells = (const float*)d_in[4];
  const float* W_head  = (const float*)d_in[5];
  const float* b_head  = (const float*)d_in[6];
  float* out = (float*)d_out;
  float* ws  = (float*)d_ws;   // 296704 bytes used

  snn_pack_k<<<(2 * HN * HN + 512 + 255) / 256, 256, 0, stream>>>(W_cells, ws);
  snn_main_k<<<128, 128, LDS_TOTAL, stream>>>(
      x, W_in, b_in, b_cells, W_head, b_head, ws, out);
}